// Round 1
// baseline (25588.977 us; speedup 1.0000x reference)
//
#include <hip/hip_runtime.h>

namespace {

constexpr int Bb = 32, Tt = 64, Dd = 1024, Hh = 1024, Vv = 32000, MX = 100;
constexpr long TBV = (long)Tt * Bb * Vv;

__device__ __forceinline__ float sigf(float x) { return 1.0f / (1.0f + expf(-x)); }

// rowidx[t*32+b] = tgt[b*T + t]  (time-major embedding gather indices)
__global__ __launch_bounds__(256) void build_rowidx(const int* __restrict__ tgt,
                                                    int* __restrict__ rowidx) {
  int i = blockIdx.x * 256 + threadIdx.x;
  if (i < Tt * Bb) {
    int t = i >> 5, b = i & 31;
    rowidx[i] = tgt[b * Tt + t];
  }
}

__global__ __launch_bounds__(64) void init_tok(int* __restrict__ tok) {
  int i = threadIdx.x;
  if (i < Bb) tok[i] = 1;  // GO token
}

// C[m,n] = sum_k A[row(m),k]*B[k,n] (+bias[n]); 64x64 tile, K%16==0, N%64==0, M%64==0
__global__ __launch_bounds__(256) void gemm_f32(
    const float* __restrict__ A, int lda, const int* __restrict__ rowIdx,
    const float* __restrict__ Bm, int ldb,
    float* __restrict__ C, long ldc, int K,
    const float* __restrict__ bias) {
  __shared__ float As[16][65];
  __shared__ float Bs[16][64];
  const int t = threadIdx.x;
  const int m0 = blockIdx.y * 64, n0 = blockIdx.x * 64;
  const int am = t >> 2, ak = (t & 3) * 4;
  long arow = rowIdx ? (long)rowIdx[m0 + am] : (long)(m0 + am);
  const float* Ap = A + arow * (long)lda;
  const int bn = t & 63, bk = (t >> 6) * 4;
  const int mg = (t >> 4) * 4, ng = (t & 15) * 4;
  float acc[4][4] = {};
  for (int k0 = 0; k0 < K; k0 += 16) {
    float4 av = *(const float4*)(Ap + k0 + ak);
    As[ak + 0][am] = av.x;
    As[ak + 1][am] = av.y;
    As[ak + 2][am] = av.z;
    As[ak + 3][am] = av.w;
    const float* Bp = Bm + (long)(k0 + bk) * ldb + n0 + bn;
#pragma unroll
    for (int r = 0; r < 4; r++) Bs[bk + r][bn] = Bp[(long)r * ldb];
    __syncthreads();
#pragma unroll
    for (int k = 0; k < 16; k++) {
      float a0 = As[k][mg + 0], a1 = As[k][mg + 1], a2 = As[k][mg + 2], a3 = As[k][mg + 3];
      float b0 = Bs[k][ng + 0], b1 = Bs[k][ng + 1], b2 = Bs[k][ng + 2], b3 = Bs[k][ng + 3];
      acc[0][0] += a0 * b0; acc[0][1] += a0 * b1; acc[0][2] += a0 * b2; acc[0][3] += a0 * b3;
      acc[1][0] += a1 * b0; acc[1][1] += a1 * b1; acc[1][2] += a1 * b2; acc[1][3] += a1 * b3;
      acc[2][0] += a2 * b0; acc[2][1] += a2 * b1; acc[2][2] += a2 * b2; acc[2][3] += a2 * b3;
      acc[3][0] += a3 * b0; acc[3][1] += a3 * b1; acc[3][2] += a3 * b2; acc[3][3] += a3 * b3;
    }
    __syncthreads();
  }
#pragma unroll
  for (int i = 0; i < 4; i++)
#pragma unroll
    for (int j = 0; j < 4; j++) {
      int m = m0 + mg + i, n = n0 + ng + j;
      float v = acc[i][j];
      if (bias) v += bias[n];
      C[(long)m * ldc + n] = v;
    }
}

// C[32,N] = (base?base[m,n]:0) + sum_k h[m,k]*B[k,n]; N%64==0, K%32==0
__global__ __launch_bounds__(256) void gemm_m32(
    const float* __restrict__ base,
    const float* __restrict__ h,
    const float* __restrict__ Bm, int ldb,
    float* __restrict__ C, int N, int K) {
  __shared__ float As[32][33];
  __shared__ float Bs[32][64];
  const int t = threadIdx.x;
  const int n0 = blockIdx.x * 64;
  const int lm = t & 31, kq = (t >> 5) * 4;
  const int bn = t & 63, kr = (t >> 6) * 8;
  const int mg = (t >> 5) * 4, ng = (t & 31) * 2;
  float acc[4][2] = {};
  for (int k0 = 0; k0 < K; k0 += 32) {
    float4 av = *(const float4*)(h + (long)lm * K + k0 + kq);
    As[kq + 0][lm] = av.x;
    As[kq + 1][lm] = av.y;
    As[kq + 2][lm] = av.z;
    As[kq + 3][lm] = av.w;
    const float* Bp = Bm + (long)(k0 + kr) * ldb + n0 + bn;
#pragma unroll
    for (int r = 0; r < 8; r++) Bs[kr + r][bn] = Bp[(long)r * ldb];
    __syncthreads();
#pragma unroll
    for (int k = 0; k < 32; k++) {
      float a0 = As[k][mg + 0], a1 = As[k][mg + 1], a2 = As[k][mg + 2], a3 = As[k][mg + 3];
      float b0 = Bs[k][ng + 0], b1 = Bs[k][ng + 1];
      acc[0][0] += a0 * b0; acc[0][1] += a0 * b1;
      acc[1][0] += a1 * b0; acc[1][1] += a1 * b1;
      acc[2][0] += a2 * b0; acc[2][1] += a2 * b1;
      acc[3][0] += a3 * b0; acc[3][1] += a3 * b1;
    }
    __syncthreads();
  }
#pragma unroll
  for (int i = 0; i < 4; i++)
#pragma unroll
    for (int j = 0; j < 2; j++) {
      int m = mg + i, n = n0 + ng + j;
      float v = acc[i][j];
      if (base) v += base[(long)m * N + n];
      C[(long)m * N + n] = v;
    }
}

// z[32,4096] = b + Wo[tok[m]] @ Wx + h @ Wh
__global__ __launch_bounds__(256) void greedy_z(
    const int* __restrict__ tok,
    const float* __restrict__ Wo,
    const float* __restrict__ Wx,
    const float* __restrict__ h,
    const float* __restrict__ Wh,
    const float* __restrict__ bias,
    float* __restrict__ z) {
  __shared__ float As[32][33];
  __shared__ float Bs[32][64];
  __shared__ int stok[32];
  const int t = threadIdx.x;
  const int n0 = blockIdx.x * 64;
  if (t < 32) stok[t] = tok[t];
  const int lm = t & 31, kq = (t >> 5) * 4;
  const int bn = t & 63, kr = (t >> 6) * 8;
  const int mg = (t >> 5) * 4, ng = (t & 31) * 2;
  float acc[4][2] = {};
  __syncthreads();
  for (int phase = 0; phase < 2; phase++) {
    const float* Arow = phase ? (h + (long)lm * Hh) : (Wo + (long)stok[lm] * Dd);
    const float* Bsrc = phase ? Wh : Wx;
    for (int k0 = 0; k0 < 1024; k0 += 32) {
      float4 av = *(const float4*)(Arow + k0 + kq);
      As[kq + 0][lm] = av.x;
      As[kq + 1][lm] = av.y;
      As[kq + 2][lm] = av.z;
      As[kq + 3][lm] = av.w;
      const float* Bp = Bsrc + (long)(k0 + kr) * 4096 + n0 + bn;
#pragma unroll
      for (int r = 0; r < 8; r++) Bs[kr + r][bn] = Bp[(long)r * 4096];
      __syncthreads();
#pragma unroll
      for (int k = 0; k < 32; k++) {
        float a0 = As[k][mg + 0], a1 = As[k][mg + 1], a2 = As[k][mg + 2], a3 = As[k][mg + 3];
        float b0 = Bs[k][ng + 0], b1 = Bs[k][ng + 1];
        acc[0][0] += a0 * b0; acc[0][1] += a0 * b1;
        acc[1][0] += a1 * b0; acc[1][1] += a1 * b1;
        acc[2][0] += a2 * b0; acc[2][1] += a2 * b1;
        acc[3][0] += a3 * b0; acc[3][1] += a3 * b1;
      }
      __syncthreads();
    }
  }
#pragma unroll
  for (int i = 0; i < 4; i++)
#pragma unroll
    for (int j = 0; j < 2; j++) {
      int m = mg + i, n = n0 + ng + j;
      z[(long)m * 4096 + n] = acc[i][j] + bias[n];
    }
}

// gates: z=[i|f|g|o] per row; c' = sig(f+1)*c + sig(i)*tanh(g); h' = sig(o)*tanh(c')
__global__ __launch_bounds__(256) void lstm_gates(
    const float* __restrict__ z, float* __restrict__ h, float* __restrict__ c,
    float* __restrict__ hs_out) {
  int idx = blockIdx.x * 256 + threadIdx.x;
  if (idx >= Bb * Hh) return;
  int m = idx >> 10, n = idx & 1023;
  const float* zr = z + (long)m * 4096;
  float zi = zr[n], zf = zr[n + 1024], zg = zr[n + 2048], zo = zr[n + 3072];
  float cn = sigf(zf + 1.0f) * c[idx] + sigf(zi) * tanhf(zg);
  float hn = sigf(zo) * tanhf(cn);
  c[idx] = cn;
  h[idx] = hn;
  if (hs_out) hs_out[idx] = hn;
}

__global__ __launch_bounds__(256) void softmax_k(
    const float* __restrict__ lgts, float* __restrict__ pr) {
  __shared__ float red[256];
  const int r = blockIdx.x, t = threadIdx.x;
  const float* x = lgts + (long)r * Vv;
  float* p = pr + (long)r * Vv;
  float mx = -3.402823466e38f;
  for (int i = t; i < Vv; i += 256) mx = fmaxf(mx, x[i]);
  red[t] = mx;
  __syncthreads();
  for (int s = 128; s > 0; s >>= 1) {
    if (t < s) red[t] = fmaxf(red[t], red[t + s]);
    __syncthreads();
  }
  mx = red[0];
  __syncthreads();
  float sum = 0.f;
  for (int i = t; i < Vv; i += 256) sum += expf(x[i] - mx);
  red[t] = sum;
  __syncthreads();
  for (int s = 128; s > 0; s >>= 1) {
    if (t < s) red[t] += red[t + s];
    __syncthreads();
  }
  float inv = 1.0f / red[0];
  for (int i = t; i < Vv; i += 256) p[i] = expf(x[i] - mx) * inv;
}

// one block per batch row; np.argmax semantics (first max wins)
__global__ __launch_bounds__(256) void argmax_k(
    const float* __restrict__ lg, int* __restrict__ tok,
    float* __restrict__ best_out) {
  __shared__ float sv[256];
  __shared__ int si[256];
  const int b = blockIdx.x, t = threadIdx.x;
  const float* row = lg + (long)b * Vv;
  float bv = -3.402823466e38f;
  int bi = 0;
  for (int i = t; i < Vv; i += 256) {
    float v = row[i];
    if (v > bv) { bv = v; bi = i; }
  }
  sv[t] = bv;
  si[t] = bi;
  __syncthreads();
  for (int s = 128; s > 0; s >>= 1) {
    if (t < s) {
      float ov = sv[t + s];
      int oi = si[t + s];
      if (ov > sv[t] || (ov == sv[t] && oi < si[t])) { sv[t] = ov; si[t] = oi; }
    }
    __syncthreads();
  }
  if (t == 0) {
    tok[b] = si[0];
    best_out[b] = (float)si[0];
  }
}

}  // namespace

extern "C" void kernel_launch(void* const* d_in, const int* in_sizes, int n_in,
                              void* d_out, int out_size, void* d_ws, size_t ws_size,
                              hipStream_t stream) {
  const int* tgt  = (const int*)d_in[0];
  const float* Wo = (const float*)d_in[1];
  const float* Wx = (const float*)d_in[2];
  const float* Wh = (const float*)d_in[3];
  const float* bb = (const float*)d_in[4];
  const float* Wp = (const float*)d_in[5];

  float* out = (float*)d_out;
  float* logits = out;                    // [T*B, V]
  float* probs = out + TBV;               // [T*B, V]
  float* best = out + 2 * TBV;            // [MX, B] as float
  // big scratch lives in the probs region (softmax runs last and overwrites)
  float* XZ = probs;                      // [T*B, 4H] = 8,388,608 floats
  float* hs = probs + (long)Tt * Bb * 4 * Hh;  // [T*B, H] = 2,097,152 floats

  float* ws = (float*)d_ws;
  float* h = ws;                          // [32,1024]
  float* c = h + Bb * Hh;                 // [32,1024]
  float* zb = c + Bb * Hh;                // [32,4096]
  float* lg = zb + Bb * 4 * Hh;           // [32,32000]
  int* tok = (int*)(lg + (long)Bb * Vv);  // [32]
  int* rowidx = tok + Bb;                 // [2048]

  // ---- phase A: teacher-forced ----
  hipMemsetAsync(h, 0, 2 * Bb * Hh * sizeof(float), stream);  // h, c = 0
  build_rowidx<<<8, 256, 0, stream>>>(tgt, rowidx);
  // XZ = gather(Wo, tgt time-major) @ Wx + b
  gemm_f32<<<dim3(4 * Hh / 64, Tt * Bb / 64), 256, 0, stream>>>(
      Wo, Dd, rowidx, Wx, 4 * Hh, XZ, 4 * Hh, Dd, bb);
  for (int t = 0; t < Tt; t++) {
    gemm_m32<<<4 * Hh / 64, 256, 0, stream>>>(XZ + (long)t * Bb * 4 * Hh, h, Wh,
                                              4 * Hh, zb, 4 * Hh, Hh);
    lstm_gates<<<Bb * Hh / 256, 256, 0, stream>>>(zb, h, c, hs + (long)t * Bb * Hh);
  }
  // logits = hs @ Wp
  gemm_f32<<<dim3(Vv / 64, Tt * Bb / 64), 256, 0, stream>>>(
      hs, Hh, nullptr, Wp, Vv, logits, Vv, Hh, nullptr);

  // ---- phase B: greedy decode ----
  hipMemsetAsync(h, 0, 2 * Bb * Hh * sizeof(float), stream);  // h, c = 0
  init_tok<<<1, 64, 0, stream>>>(tok);
  for (int s = 0; s < MX; s++) {
    greedy_z<<<4 * Hh / 64, 256, 0, stream>>>(tok, Wo, Wx, h, Wh, bb, zb);
    lstm_gates<<<Bb * Hh / 256, 256, 0, stream>>>(zb, h, c, nullptr);
    gemm_m32<<<Vv / 64, 256, 0, stream>>>(nullptr, h, Wp, Vv, lg, Vv, Hh);
    argmax_k<<<Bb, 256, 0, stream>>>(lg, tok, best + s * Bb);
  }

  // ---- softmax last (it overwrites the scratch region) ----
  softmax_k<<<Tt * Bb, 256, 0, stream>>>(logits, probs);
}

// Round 2
// 11540.042 us; speedup vs baseline: 2.2174x; 2.2174x over previous
//
#include <hip/hip_runtime.h>

namespace {

constexpr int Bb = 32, Tt = 64, Dd = 1024, Hh = 1024, Vv = 32000, MX = 100;
constexpr long TBV = (long)Tt * Bb * Vv;

typedef __bf16 bf16x8 __attribute__((ext_vector_type(8)));
typedef float floatx4 __attribute__((ext_vector_type(4)));

__device__ __forceinline__ float sigf(float x) { return 1.0f / (1.0f + expf(-x)); }

__device__ __forceinline__ __bf16 f2bf(float x) {
  unsigned u = __builtin_bit_cast(unsigned, x);
  unsigned short r = (unsigned short)((u + 0x7FFFu + ((u >> 16) & 1u)) >> 16);
  return __builtin_bit_cast(__bf16, r);
}

__global__ __launch_bounds__(64) void init_tok(int* __restrict__ tok) {
  int i = threadIdx.x;
  if (i < Bb) tok[i] = 1;  // GO token
}

// X[row, k] = bf16(Wo[tgt[b*T+t], k]) with row = t*32+b (time-major)
__global__ __launch_bounds__(256) void gather_cast_x(
    const int* __restrict__ tgt, const float* __restrict__ Wo,
    __bf16* __restrict__ X) {
  int i = blockIdx.x * 256 + threadIdx.x;  // 262144 chunks of 8
  int row = i >> 7, ko = (i & 127) * 8;
  int tt = row >> 5, b = row & 31;
  const float* src = Wo + (long)tgt[b * Tt + tt] * Dd + ko;
  float4 v0 = *(const float4*)src, v1 = *(const float4*)(src + 4);
  bf16x8 w;
  w[0] = f2bf(v0.x); w[1] = f2bf(v0.y); w[2] = f2bf(v0.z); w[3] = f2bf(v0.w);
  w[4] = f2bf(v1.x); w[5] = f2bf(v1.y); w[6] = f2bf(v1.z); w[7] = f2bf(v1.w);
  *(bf16x8*)(X + (long)row * Dd + ko) = w;
}

// in: fp32 [K,N] row-major  ->  out: bf16 [N,K] row-major.  grid(N/64, K/64)
__global__ __launch_bounds__(256) void transpose_cast(
    const float* __restrict__ in, __bf16* __restrict__ out, int K, int N) {
  __shared__ __bf16 tile[64][72];  // [n][k]
  int k0 = blockIdx.y * 64, n0 = blockIdx.x * 64;
  int t = threadIdx.x;
#pragma unroll
  for (int cc = 0; cc < 4; cc++) {
    int cid = t + cc * 256;  // 1024 float4 chunks
    int kk = cid >> 4, nn = (cid & 15) * 4;
    float4 v = *(const float4*)(in + (long)(k0 + kk) * N + n0 + nn);
    tile[nn + 0][kk] = f2bf(v.x);
    tile[nn + 1][kk] = f2bf(v.y);
    tile[nn + 2][kk] = f2bf(v.z);
    tile[nn + 3][kk] = f2bf(v.w);
  }
  __syncthreads();
#pragma unroll
  for (int cc = 0; cc < 2; cc++) {
    int cid = t + cc * 256;  // 512 bf16x8 chunks
    int nn = cid >> 3, kk = (cid & 7) * 8;
    bf16x8 w;
#pragma unroll
    for (int j = 0; j < 8; j++) w[j] = tile[nn][kk + j];
    *(bf16x8*)(out + (long)(n0 + nn) * K + k0 + kk) = w;
  }
}

// C[M,N] fp32 = A[M,K]bf16 @ BT[N,K]bf16^T (+bias). 128x128 tile, 4 waves.
// MFMA 16x16x32 bf16; A-frag: m=lane&15,k=quad*8+j; B-frag: n=lane&15,k=quad*8+j;
// C/D: col=lane&15, row=quad*4+reg  (m89/m91-verified layouts)
__global__ __launch_bounds__(256) void gemm_mfma(
    const __bf16* __restrict__ A, const __bf16* __restrict__ BT,
    float* __restrict__ C, int ldc, int K, const float* __restrict__ bias) {
  __shared__ __bf16 As[128 * 40];
  __shared__ __bf16 Bs[128 * 40];
  const int t = threadIdx.x;
  const int lane = t & 63, wave = t >> 6;
  const int m0 = blockIdx.y * 128, n0 = blockIdx.x * 128;
  const int wm = (wave >> 1) * 64, wn = (wave & 1) * 64;
  const int fr = lane & 15;        // frag row (m or n within 16-tile)
  const int fk = (lane >> 4) * 8;  // frag k offset
  floatx4 acc[4][4] = {};
  for (int k0 = 0; k0 < K; k0 += 32) {
#pragma unroll
    for (int cc = 0; cc < 2; cc++) {
      int cid = t + cc * 256;
      int row = cid >> 2, ko = (cid & 3) * 8;
      *(bf16x8*)(As + row * 40 + ko) =
          *(const bf16x8*)(A + (long)(m0 + row) * K + k0 + ko);
      *(bf16x8*)(Bs + row * 40 + ko) =
          *(const bf16x8*)(BT + (long)(n0 + row) * K + k0 + ko);
    }
    __syncthreads();
    bf16x8 af[4], bg[4];
#pragma unroll
    for (int i = 0; i < 4; i++) {
      af[i] = *(const bf16x8*)(As + (wm + i * 16 + fr) * 40 + fk);
      bg[i] = *(const bf16x8*)(Bs + (wn + i * 16 + fr) * 40 + fk);
    }
#pragma unroll
    for (int i = 0; i < 4; i++)
#pragma unroll
      for (int j = 0; j < 4; j++)
        acc[i][j] = __builtin_amdgcn_mfma_f32_16x16x32_bf16(af[i], bg[j],
                                                            acc[i][j], 0, 0, 0);
    __syncthreads();
  }
  const int cr = (lane >> 4) * 4;
#pragma unroll
  for (int i = 0; i < 4; i++)
#pragma unroll
    for (int j = 0; j < 4; j++) {
      int n = n0 + wn + j * 16 + fr;
      float bv = bias ? bias[n] : 0.f;
#pragma unroll
      for (int r = 0; r < 4; r++) {
        int m = m0 + wm + i * 16 + cr + r;
        C[(long)m * ldc + n] = acc[i][j][r] + bv;
      }
    }
}

// phase-A recurrent partial: zp[ks][32][4096] = h[32, ks*256..+256] @ Wh[...]
// grid(64, 4)
__global__ __launch_bounds__(256) void zpartA(
    const float* __restrict__ h, const float* __restrict__ Wh,
    float* __restrict__ zp) {
  __shared__ float As[32][33];
  __shared__ float Bs[32][64];
  const int t = threadIdx.x;
  const int n0 = blockIdx.x * 64, ks = blockIdx.y, kbase = ks * 256;
  const int lm = t & 31, kq = (t >> 5) * 4;
  const int bn = t & 63, kr = (t >> 6) * 8;
  const int mg = (t >> 5) * 4, ng = (t & 31) * 2;
  float acc[4][2] = {};
  for (int k0 = 0; k0 < 256; k0 += 32) {
    float4 av = *(const float4*)(h + (long)lm * Hh + kbase + k0 + kq);
    As[kq + 0][lm] = av.x; As[kq + 1][lm] = av.y;
    As[kq + 2][lm] = av.z; As[kq + 3][lm] = av.w;
    const float* Bp = Wh + (long)(kbase + k0 + kr) * 4096 + n0 + bn;
#pragma unroll
    for (int r = 0; r < 8; r++) Bs[kr + r][bn] = Bp[(long)r * 4096];
    __syncthreads();
#pragma unroll
    for (int k = 0; k < 32; k++) {
      float a0 = As[k][mg], a1 = As[k][mg + 1], a2 = As[k][mg + 2], a3 = As[k][mg + 3];
      float b0 = Bs[k][ng], b1 = Bs[k][ng + 1];
      acc[0][0] += a0 * b0; acc[0][1] += a0 * b1;
      acc[1][0] += a1 * b0; acc[1][1] += a1 * b1;
      acc[2][0] += a2 * b0; acc[2][1] += a2 * b1;
      acc[3][0] += a3 * b0; acc[3][1] += a3 * b1;
    }
    __syncthreads();
  }
#pragma unroll
  for (int i = 0; i < 4; i++)
#pragma unroll
    for (int j = 0; j < 2; j++)
      zp[((long)ks * 32 + mg + i) * 4096 + n0 + ng + j] = acc[i][j];
}

// greedy z partial over combined K=2048 (x@Wx then h@Wh). grid(64, 8)
__global__ __launch_bounds__(256) void zpartB(
    const int* __restrict__ tok, const float* __restrict__ Wo,
    const float* __restrict__ Wx, const float* __restrict__ h,
    const float* __restrict__ Wh, float* __restrict__ zp) {
  __shared__ float As[32][33];
  __shared__ float Bs[32][64];
  __shared__ int stok[32];
  const int t = threadIdx.x;
  const int n0 = blockIdx.x * 64, ks = blockIdx.y;
  if (t < 32) stok[t] = tok[t];
  const int lm = t & 31, kq = (t >> 5) * 4;
  const int bn = t & 63, kr = (t >> 6) * 8;
  const int mg = (t >> 5) * 4, ng = (t & 31) * 2;
  float acc[4][2] = {};
  __syncthreads();
  const float* Arow;
  const float* Bsrc;
  int kbase;
  if (ks < 4) {
    kbase = ks * 256;
    Bsrc = Wx;
    Arow = Wo + (long)stok[lm] * Dd + kbase;
  } else {
    kbase = (ks - 4) * 256;
    Bsrc = Wh;
    Arow = h + (long)lm * Hh + kbase;
  }
  for (int k0 = 0; k0 < 256; k0 += 32) {
    float4 av = *(const float4*)(Arow + k0 + kq);
    As[kq + 0][lm] = av.x; As[kq + 1][lm] = av.y;
    As[kq + 2][lm] = av.z; As[kq + 3][lm] = av.w;
    const float* Bp = Bsrc + (long)(kbase + k0 + kr) * 4096 + n0 + bn;
#pragma unroll
    for (int r = 0; r < 8; r++) Bs[kr + r][bn] = Bp[(long)r * 4096];
    __syncthreads();
#pragma unroll
    for (int k = 0; k < 32; k++) {
      float a0 = As[k][mg], a1 = As[k][mg + 1], a2 = As[k][mg + 2], a3 = As[k][mg + 3];
      float b0 = Bs[k][ng], b1 = Bs[k][ng + 1];
      acc[0][0] += a0 * b0; acc[0][1] += a0 * b1;
      acc[1][0] += a1 * b0; acc[1][1] += a1 * b1;
      acc[2][0] += a2 * b0; acc[2][1] += a2 * b1;
      acc[3][0] += a3 * b0; acc[3][1] += a3 * b1;
    }
    __syncthreads();
  }
#pragma unroll
  for (int i = 0; i < 4; i++)
#pragma unroll
    for (int j = 0; j < 2; j++)
      zp[((long)ks * 32 + mg + i) * 4096 + n0 + ng + j] = acc[i][j];
}

// phase-A gates: z = XZ_t + sum of 4 partials (bias already in XZ)
__global__ __launch_bounds__(256) void gatesA(
    const float* __restrict__ base, const float* __restrict__ zp,
    float* __restrict__ h, float* __restrict__ c, __bf16* __restrict__ hsb) {
  int idx = blockIdx.x * 256 + threadIdx.x;  // 32768
  int m = idx >> 10, n = idx & 1023;
  long o = (long)m * 4096 + n;
  float z[4];
#pragma unroll
  for (int g = 0; g < 4; g++) {
    float v = base[o + g * 1024];
#pragma unroll
    for (int ks = 0; ks < 4; ks++) v += zp[(long)ks * 131072 + o + g * 1024];
    z[g] = v;
  }
  float cn = sigf(z[1] + 1.0f) * c[idx] + sigf(z[0]) * tanhf(z[2]);
  float hn = sigf(z[3]) * tanhf(cn);
  c[idx] = cn;
  h[idx] = hn;
  hsb[idx] = f2bf(hn);
}

// greedy gates: z = sum of 8 partials + bias
__global__ __launch_bounds__(256) void gatesB(
    const float* __restrict__ zp, const float* __restrict__ bias,
    float* __restrict__ h, float* __restrict__ c) {
  int idx = blockIdx.x * 256 + threadIdx.x;
  int m = idx >> 10, n = idx & 1023;
  long o = (long)m * 4096 + n;
  float z[4];
#pragma unroll
  for (int g = 0; g < 4; g++) {
    float v = bias[g * 1024 + n];
#pragma unroll
    for (int ks = 0; ks < 8; ks++) v += zp[(long)ks * 131072 + o + g * 1024];
    z[g] = v;
  }
  float cn = sigf(z[1] + 1.0f) * c[idx] + sigf(z[0]) * tanhf(z[2]);
  float hn = sigf(z[3]) * tanhf(cn);
  c[idx] = cn;
  h[idx] = hn;
}

// greedy lg = h @ Wp with fused per-64-col-tile argmax; no lg materialization.
// grid(500). pv/pi: [32][500]
__global__ __launch_bounds__(256) void lg_argmax_part(
    const float* __restrict__ h, const float* __restrict__ Wp,
    float* __restrict__ pv, int* __restrict__ pi) {
  __shared__ float As[32][33];
  __shared__ float Bs[32][64];
  __shared__ float rv[32][33];
  __shared__ int ri[32][33];
  const int t = threadIdx.x;
  const int n0 = blockIdx.x * 64;
  const int lm = t & 31, kq = (t >> 5) * 4;
  const int bn = t & 63, kr = (t >> 6) * 8;
  const int mg = (t >> 5) * 4, ng = (t & 31) * 2;
  float acc[4][2] = {};
  for (int k0 = 0; k0 < 1024; k0 += 32) {
    float4 av = *(const float4*)(h + (long)lm * Hh + k0 + kq);
    As[kq + 0][lm] = av.x; As[kq + 1][lm] = av.y;
    As[kq + 2][lm] = av.z; As[kq + 3][lm] = av.w;
    const float* Bp = Wp + (long)(k0 + kr) * Vv + n0 + bn;
#pragma unroll
    for (int r = 0; r < 8; r++) Bs[kr + r][bn] = Bp[(long)r * Vv];
    __syncthreads();
#pragma unroll
    for (int k = 0; k < 32; k++) {
      float a0 = As[k][mg], a1 = As[k][mg + 1], a2 = As[k][mg + 2], a3 = As[k][mg + 3];
      float b0 = Bs[k][ng], b1 = Bs[k][ng + 1];
      acc[0][0] += a0 * b0; acc[0][1] += a0 * b1;
      acc[1][0] += a1 * b0; acc[1][1] += a1 * b1;
      acc[2][0] += a2 * b0; acc[2][1] += a2 * b1;
      acc[3][0] += a3 * b0; acc[3][1] += a3 * b1;
    }
    __syncthreads();
  }
#pragma unroll
  for (int i = 0; i < 4; i++) {
    float v0 = acc[i][0], v1 = acc[i][1];
    int c0 = n0 + ng;
    float bvv = (v1 > v0) ? v1 : v0;
    int bii = (v1 > v0) ? (c0 + 1) : c0;
    rv[mg + i][t & 31] = bvv;
    ri[mg + i][t & 31] = bii;
  }
  __syncthreads();
  if (t < 32) {
    float bvv = -3.402823466e38f;
    int bii = 0x7fffffff;
    for (int j = 0; j < 32; j++) {
      float v = rv[t][j];
      int id = ri[t][j];
      if (v > bvv || (v == bvv && id < bii)) { bvv = v; bii = id; }
    }
    pv[t * 500 + blockIdx.x] = bvv;
    pi[t * 500 + blockIdx.x] = bii;
  }
}

// reduce 500 tile-argmaxes per batch row (np first-wins). grid(32)
__global__ __launch_bounds__(256) void argmax_fin(
    const float* __restrict__ pv, const int* __restrict__ pi,
    int* __restrict__ tok, float* __restrict__ best) {
  __shared__ float sv[256];
  __shared__ int si[256];
  int row = blockIdx.x, t = threadIdx.x;
  float bvv = -3.402823466e38f;
  int bii = 0x7fffffff;
  for (int j = t; j < 500; j += 256) {
    float v = pv[row * 500 + j];
    int id = pi[row * 500 + j];
    if (v > bvv || (v == bvv && id < bii)) { bvv = v; bii = id; }
  }
  sv[t] = bvv; si[t] = bii;
  __syncthreads();
  for (int s = 128; s > 0; s >>= 1) {
    if (t < s) {
      float v = sv[t + s]; int id = si[t + s];
      if (v > sv[t] || (v == sv[t] && id < si[t])) { sv[t] = v; si[t] = id; }
    }
    __syncthreads();
  }
  if (t == 0) { tok[row] = si[0]; best[row] = (float)si[0]; }
}

// online two-pass softmax. grid(T*B)
__global__ __launch_bounds__(256) void softmax_k(
    const float* __restrict__ lgts, float* __restrict__ pr) {
  __shared__ float rm[256], rs[256];
  const int r = blockIdx.x, t = threadIdx.x;
  const float* x = lgts + (long)r * Vv;
  float* p = pr + (long)r * Vv;
  float mx = -3.402823466e38f, sm = 0.f;
  for (int i = t; i < Vv; i += 256) {
    float v = x[i];
    if (v > mx) { sm = sm * __expf(mx - v) + 1.f; mx = v; }
    else sm += __expf(v - mx);
  }
  rm[t] = mx; rs[t] = sm;
  __syncthreads();
  for (int s = 128; s > 0; s >>= 1) {
    if (t < s) {
      float m2 = rm[t + s], s2 = rs[t + s];
      float M = fmaxf(rm[t], m2);
      rs[t] = rs[t] * __expf(rm[t] - M) + s2 * __expf(m2 - M);
      rm[t] = M;
    }
    __syncthreads();
  }
  float M = rm[0], inv = 1.f / rs[0];
  for (int i = t; i < Vv; i += 256) p[i] = __expf(x[i] - M) * inv;
}

}  // namespace

extern "C" void kernel_launch(void* const* d_in, const int* in_sizes, int n_in,
                              void* d_out, int out_size, void* d_ws, size_t ws_size,
                              hipStream_t stream) {
  const int* tgt  = (const int*)d_in[0];
  const float* Wo = (const float*)d_in[1];
  const float* Wx = (const float*)d_in[2];
  const float* Wh = (const float*)d_in[3];
  const float* bb = (const float*)d_in[4];
  const float* Wp = (const float*)d_in[5];

  float* out = (float*)d_out;
  float* logits = out;          // [T*B, V]
  float* probs = out + TBV;     // [T*B, V]
  float* best = out + 2 * TBV;  // [MX, B] as float

  // big scratch in the probs region (softmax runs last, overwrites)
  float* XZ = probs;                                 // [2048,4096] fp32
  __bf16* Xtm   = (__bf16*)(probs + 8388608);        // [2048,1024] bf16
  __bf16* hs_bf = (__bf16*)(probs + 8388608 + 1048576);
  __bf16* WxT   = (__bf16*)(probs + 8388608 + 2 * 1048576);   // [4096,1024]
  __bf16* WpT   = (__bf16*)(probs + 8388608 + 4 * 1048576);   // [32000,1024]

  float* ws = (float*)d_ws;
  float* h = ws;                           // [32,1024]
  float* c = h + Bb * Hh;                  // [32,1024]
  float* zp = c + Bb * Hh;                 // [8][32][4096]
  float* pv = zp + 8 * Bb * 4 * Hh;        // [32][500]
  int* pi = (int*)(pv + 32 * 500);         // [32][500]
  int* tok = pi + 32 * 500;                // [32]

  // ---- one-time casts / gathers ----
  gather_cast_x<<<1024, 256, 0, stream>>>(tgt, Wo, Xtm);
  transpose_cast<<<dim3(64, 16), 256, 0, stream>>>(Wx, WxT, Dd, 4 * Hh);
  transpose_cast<<<dim3(500, 16), 256, 0, stream>>>(Wp, WpT, Hh, Vv);

  // ---- phase A: teacher-forced ----
  hipMemsetAsync(h, 0, 2 * Bb * Hh * sizeof(float), stream);  // h, c = 0
  // XZ = Xtm @ Wx + b   (bf16 MFMA)
  gemm_mfma<<<dim3(32, 16), 256, 0, stream>>>(Xtm, WxT, XZ, 4 * Hh, Dd, bb);
  for (int t = 0; t < Tt; t++) {
    zpartA<<<dim3(64, 4), 256, 0, stream>>>(h, Wh, zp);
    gatesA<<<128, 256, 0, stream>>>(XZ + (long)t * Bb * 4 * Hh, zp, h, c,
                                    hs_bf + (long)t * Bb * Hh);
  }
  // logits = hs @ Wp   (bf16 MFMA)
  gemm_mfma<<<dim3(250, 16), 256, 0, stream>>>(hs_bf, WpT, logits, Vv, Hh,
                                               nullptr);

  // ---- phase B: greedy decode (all fp32 — argmax fidelity) ----
  hipMemsetAsync(h, 0, 2 * Bb * Hh * sizeof(float), stream);
  init_tok<<<1, 64, 0, stream>>>(tok);
  for (int s = 0; s < MX; s++) {
    zpartB<<<dim3(64, 8), 256, 0, stream>>>(tok, Wo, Wx, h, Wh, zp);
    gatesB<<<128, 256, 0, stream>>>(zp, bb, h, c);
    lg_argmax_part<<<500, 256, 0, stream>>>(h, Wp, pv, pi);
    argmax_fin<<<32, 256, 0, stream>>>(pv, pi, tok, best + s * Bb);
  }

  // ---- softmax last (scratch region is dead now) ----
  softmax_k<<<Tt * Bb, 256, 0, stream>>>(logits, probs);
}